// Round 19
// baseline (226.055 us; speedup 1.0000x reference)
//
#include <hip/hip_runtime.h>

// ---------------------------------------------------------------------------
// MultiHeadAttentionWithRPR: B=4, S=1024, D=1024, H=16, hd=64, CLIP=16
// R24 = R23 (best, 196.8us) + attn QBLK 32->64 (4 row-groups, 2 pairs per
// tile). R13 proved the lever (16->32 = -19%); R15's 64 failed ONLY on spill
// under launch_bounds(64,2)'s 128-VGPR cap; R19 proved launch_bounds(64)
// avoids it (~250 VGPR demand < 256). Grid 1024, remap b=x>>8: each CU holds
// exactly one block per batch (4/CU resident) -> perfect vlen balance.
// General window for 64 rows: (j0 > i0-79) && (j0 < i0+79).
// Carries R22/R23 attn fixes: exp2 fold (Q scale 0.125*log2e), register
// clip-tails, plain-add interior bins (race-free per-lane-distinct (row,t)).
// proj 128x128 / out_proj 64x128 / convert / fragment K/V unchanged.
// ---------------------------------------------------------------------------

typedef __attribute__((ext_vector_type(8))) short short8;   // 8 bf16
typedef __attribute__((ext_vector_type(4))) float floatx4;  // 4 f32 acc

__device__ __forceinline__ unsigned short f2bf(float f) {
  union { float f; unsigned u; } v; v.f = f;
  return (unsigned short)((v.u + 0x7fffu + ((v.u >> 16) & 1u)) >> 16); // RNE
}
__device__ __forceinline__ unsigned packbf(float lo, float hi) {
  return ((unsigned)f2bf(hi) << 16) | (unsigned)f2bf(lo);
}

__device__ __forceinline__ void gld16(const void* g, void* l) {
  __builtin_amdgcn_global_load_lds(
      (const __attribute__((address_space(1))) unsigned*)g,
      (__attribute__((address_space(3))) unsigned*)l, 16, 0, 0);
}

// ws layout (ushort element offsets)
#define WS_XQ  ((size_t)0)
#define WS_XK  ((size_t)4194304)
#define WS_XV  ((size_t)8388608)
#define WS_W   ((size_t)12582912)   // 4 x 1048576 (Wq,Wk,Wv,Wo)
#define WS_EKB ((size_t)16777216)   // 64x64 bf16 (rows t, zero-padded t>=33)
#define WS_EVT ((size_t)16781312)   // 64x64 bf16 (rows d, cols t, zero-padded)
#define WS_QB  ((size_t)16785408)
#define WS_KB  ((size_t)20979712)   // Kf fragment layout, 64 bh x 65536
#define WS_VT  ((size_t)25174016)   // Vf fragment layout, 64 bh x 65536
#define WS_OB  ((size_t)0)          // overlay on XQ (proj finished with it)

// ---------------------------------------------------------------------------
// One launch for all dtype conversions. z: 0..2 X(q,k,v), 3..6 W(q,k,v,o),
// 7 Ek/Ev pack. K/V rows >= vlen skipped (never used unmasked downstream).
// ---------------------------------------------------------------------------
__global__ __launch_bounds__(256) void convert_all_kernel(
    const float* __restrict__ q, const float* __restrict__ k,
    const float* __restrict__ v,
    const float* __restrict__ wq, const float* __restrict__ wk,
    const float* __restrict__ wv, const float* __restrict__ wo,
    const float* __restrict__ Ek, const float* __restrict__ Ev,
    const int* __restrict__ valid_lens, unsigned short* __restrict__ ws) {
  int z = blockIdx.z;
  if (z < 3) {
    const float* src = z == 0 ? q : (z == 1 ? k : v);
    unsigned short* dst = ws + (size_t)z * 4194304;
    size_t i = ((size_t)blockIdx.x * 256 + threadIdx.x) * 8;
    if (z > 0) {  // K/V: row s of batch b unused if s >= vlen
      int b = (int)(i >> 20), s = (int)((i >> 10) & 1023);
      if (s >= valid_lens[b]) return;
    }
    float4 a = *(const float4*)(src + i);
    float4 bb = *(const float4*)(src + i + 4);
    uint4 o = { packbf(a.x, a.y), packbf(a.z, a.w), packbf(bb.x, bb.y), packbf(bb.z, bb.w) };
    *(uint4*)(dst + i) = o;
  } else if (z < 7) {
    if (blockIdx.x >= 512) return;
    const float* src = (z == 3) ? wq : (z == 4 ? wk : (z == 5 ? wv : wo));
    unsigned short* dst = ws + WS_W + (size_t)(z - 3) * 1048576;
    size_t i = ((size_t)blockIdx.x * 256 + threadIdx.x) * 8;
    float4 a = *(const float4*)(src + i);
    float4 bb = *(const float4*)(src + i + 4);
    uint4 o = { packbf(a.x, a.y), packbf(a.z, a.w), packbf(bb.x, bb.y), packbf(bb.z, bb.w) };
    *(uint4*)(dst + i) = o;
  } else {
    if (blockIdx.x >= 4) return;
    int gid = blockIdx.x * 256 + threadIdx.x;   // 0..1023, x8 = Ekb+Evt
    unsigned short* ekb = ws + WS_EKB;
    int i0 = gid * 8;
    unsigned short vals[8];
#pragma unroll
    for (int u = 0; u < 8; u++) {
      int i = i0 + u;
      if (i < 4096) {                    // Ekb[t][d]
        int t = i >> 6, d = i & 63;
        vals[u] = (t < 33) ? f2bf(Ek[t * 64 + d]) : (unsigned short)0;
      } else {                           // Evt[d][t]
        int j = i - 4096;
        int d = j >> 6, t = j & 63;
        vals[u] = (t < 33) ? f2bf(Ev[t * 64 + d]) : (unsigned short)0;
      }
    }
    *(uint4*)(ekb + i0) = *(uint4*)vals;
  }
}

// ---------------------------------------------------------------------------
// NT GEMM 128x128 tile, BK=32, global_load_lds staging. A,W bf16 [.,1024].
// mode 0: bf16 row-major * scale (Q). mode 1: K fragment layout Kf.
// mode 2: V fragment layout Vf. mode 3: f32 row-major (final out).
// Fragment layouts (shorts): [bh*65536 + (kt*8 + frag*2 + half)*512
//   + lane*8 + dd], lane = lq*16 + lr of the CONSUMING attn wave:
//   Kf: s = kt*64 + frag*16 + lr, d = half*32 + lq*8 + dd
//   Vf: d = frag*16 + lr,         s = kt*64 + half*32 + lq*8 + dd
// ---------------------------------------------------------------------------
__device__ __forceinline__ void gemm128_body(
    const unsigned short* __restrict__ A, const unsigned short* __restrict__ W,
    unsigned short* __restrict__ Cb, float* __restrict__ Cf, int mode, float scale) {
  __shared__ unsigned short sA[128 * 32];
  __shared__ unsigned short sB[128 * 32];
  const int tid = threadIdx.x, wave = tid >> 6, lane = tid & 63;
  const int lr = lane & 15, lq = lane >> 4;
  const int wr = wave >> 1, wc = wave & 1;
  const int m0 = blockIdx.y * 128, n0 = blockIdx.x * 128;
  const int srow = lane >> 2, scol = (lane & 3) * 8;

  const unsigned short* gA0 = A + (size_t)(m0 + wave * 16 + srow) * 1024 + scol;
  const unsigned short* gA1 = gA0 + (size_t)64 * 1024;
  const unsigned short* gB0 = W + (size_t)(n0 + wave * 16 + srow) * 1024 + scol;
  const unsigned short* gB1 = gB0 + (size_t)64 * 1024;
  unsigned short* lA0 = sA + wave * 512;  unsigned short* lA1 = lA0 + 2048;
  unsigned short* lB0 = sB + wave * 512;  unsigned short* lB1 = lB0 + 2048;

  floatx4 acc[4][4];
#pragma unroll
  for (int mi = 0; mi < 4; mi++)
#pragma unroll
    for (int ni = 0; ni < 4; ni++) acc[mi][ni] = (floatx4){0.f, 0.f, 0.f, 0.f};

  for (int k0 = 0; k0 < 1024; k0 += 32) {
    gld16(gA0 + k0, lA0); gld16(gA1 + k0, lA1);
    gld16(gB0 + k0, lB0); gld16(gB1 + k0, lB1);
    __syncthreads();
    short8 af[4], bf[4];
#pragma unroll
    for (int mi = 0; mi < 4; mi++)
      af[mi] = *(const short8*)(sA + (wr * 64 + mi * 16 + lr) * 32 + lq * 8);
#pragma unroll
    for (int ni = 0; ni < 4; ni++)
      bf[ni] = *(const short8*)(sB + (wc * 64 + ni * 16 + lr) * 32 + lq * 8);
#pragma unroll
    for (int mi = 0; mi < 4; mi++)
#pragma unroll
      for (int ni = 0; ni < 4; ni++)
        acc[mi][ni] = __builtin_amdgcn_mfma_f32_16x16x32_bf16(af[mi], bf[ni], acc[mi][ni], 0, 0, 0);
    __syncthreads();
  }

  if (mode == 2) {       // V -> Vf fragment layout, one 8B store per quad
#pragma unroll
    for (int mi = 0; mi < 4; mi++)
#pragma unroll
      for (int ni = 0; ni < 4; ni++) {
        int col = n0 + wc * 64 + ni * 16 + lr;
        int h = col >> 6, d = col & 63;
        int rowg = m0 + wr * 64 + mi * 16 + lq * 4;
        int b = rowg >> 10, s = rowg & 1023;   // s..s+3, s % 4 == 0
        int bh = b * 16 + h;
        uint2 pk;
        pk.x = packbf(acc[mi][ni][0], acc[mi][ni][1]);
        pk.y = packbf(acc[mi][ni][2], acc[mi][ni][3]);
        size_t off = (size_t)bh * 65536
                   + (size_t)((s >> 6) * 8 + (d >> 4) * 2 + ((s >> 5) & 1)) * 512
                   + (size_t)((((s >> 3) & 3) * 16) + (d & 15)) * 8 + (s & 7);
        *(uint2*)(Cb + off) = pk;
      }
  } else if (mode == 1) { // K -> Kf fragment layout, scalar stores
#pragma unroll
    for (int mi = 0; mi < 4; mi++)
#pragma unroll
      for (int ni = 0; ni < 4; ni++)
#pragma unroll
        for (int r = 0; r < 4; r++) {
          int rowg = m0 + wr * 64 + mi * 16 + lq * 4 + r;
          int col = n0 + wc * 64 + ni * 16 + lr;
          int b = rowg >> 10, s = rowg & 1023;
          int h = col >> 6, d = col & 63;
          int bh = b * 16 + h;
          size_t off = (size_t)bh * 65536
                     + (size_t)((s >> 6) * 8 + ((s & 63) >> 4) * 2 + (d >> 5)) * 512
                     + (size_t)((((d & 31) >> 3) * 16) + (s & 15)) * 8 + (d & 7);
          Cb[off] = f2bf(acc[mi][ni][r]);
        }
  } else if (mode == 3) {
#pragma unroll
    for (int mi = 0; mi < 4; mi++)
#pragma unroll
      for (int ni = 0; ni < 4; ni++)
#pragma unroll
        for (int r = 0; r < 4; r++) {
          int row = m0 + wr * 64 + mi * 16 + lq * 4 + r;
          int col = n0 + wc * 64 + ni * 16 + lr;
          Cf[(size_t)row * 1024 + col] = acc[mi][ni][r];
        }
  } else {               // mode 0: Q, row-major bf16 * scale
#pragma unroll
    for (int mi = 0; mi < 4; mi++)
#pragma unroll
      for (int ni = 0; ni < 4; ni++)
#pragma unroll
        for (int r = 0; r < 4; r++) {
          int row = m0 + wr * 64 + mi * 16 + lq * 4 + r;
          int col = n0 + wc * 64 + ni * 16 + lr;
          Cb[(size_t)row * 1024 + col] = f2bf(acc[mi][ni][r] * scale);
        }
  }
}

__global__ __launch_bounds__(256, 3) void proj_qkv_kernel(
    unsigned short* __restrict__ ws, const int* __restrict__ valid_lens) {
  int z = blockIdx.z;
  if (z > 0) {  // K/V: whole tile unused if its first row >= vlen
    int m0 = blockIdx.y * 128;
    if ((m0 & 1023) >= valid_lens[m0 >> 10]) return;
  }
  const unsigned short* A = ws + (size_t)z * 4194304;
  const unsigned short* W = ws + WS_W + (size_t)z * 1048576;
  unsigned short* Cb = (z == 0) ? ws + WS_QB : (z == 1 ? ws + WS_KB : ws + WS_VT);
  int mode = (z == 2) ? 2 : (z == 0 ? 0 : 1);
  // fold 1/sqrt(hd) AND log2(e) into Q ONLY: s2 = log2e*(q.k + q.Ek)/8,
  // softmax uses exp2(s2) == exp(s) exactly. K stays unscaled.
  float scale = (z == 0) ? (0.125f * 1.4426950408889634f) : 1.0f;
  gemm128_body(A, W, Cb, nullptr, mode, scale);
}

// ---------------------------------------------------------------------------
// out_proj: 64x128 tile (512 blocks = 2/CU). 4 waves as 2x2 over (64,128);
// each wave 32x64 = acc[2][4]. f32 row-major epilogue.
// ---------------------------------------------------------------------------
__global__ __launch_bounds__(256, 4) void out_proj_kernel(
    const unsigned short* __restrict__ Ob, const unsigned short* __restrict__ Wo,
    float* __restrict__ out) {
  __shared__ unsigned short sA[64 * 32];
  __shared__ unsigned short sB[128 * 32];
  const int tid = threadIdx.x, wave = tid >> 6, lane = tid & 63;
  const int lr = lane & 15, lq = lane >> 4;
  const int wr = wave >> 1, wc = wave & 1;
  const int m0 = blockIdx.y * 64, n0 = blockIdx.x * 128;
  const int srow = lane >> 2, scol = (lane & 3) * 8;

  const unsigned short* gA0 = Ob + (size_t)(m0 + wave * 16 + srow) * 1024 + scol;
  const unsigned short* gB0 = Wo + (size_t)(n0 + wave * 16 + srow) * 1024 + scol;
  const unsigned short* gB1 = gB0 + (size_t)64 * 1024;
  unsigned short* lA0 = sA + wave * 512;
  unsigned short* lB0 = sB + wave * 512;  unsigned short* lB1 = lB0 + 2048;

  floatx4 acc[2][4];
#pragma unroll
  for (int mi = 0; mi < 2; mi++)
#pragma unroll
    for (int ni = 0; ni < 4; ni++) acc[mi][ni] = (floatx4){0.f, 0.f, 0.f, 0.f};

  for (int k0 = 0; k0 < 1024; k0 += 32) {
    gld16(gA0 + k0, lA0);
    gld16(gB0 + k0, lB0); gld16(gB1 + k0, lB1);
    __syncthreads();
    short8 af[2], bf[4];
#pragma unroll
    for (int mi = 0; mi < 2; mi++)
      af[mi] = *(const short8*)(sA + (wr * 32 + mi * 16 + lr) * 32 + lq * 8);
#pragma unroll
    for (int ni = 0; ni < 4; ni++)
      bf[ni] = *(const short8*)(sB + (wc * 64 + ni * 16 + lr) * 32 + lq * 8);
#pragma unroll
    for (int mi = 0; mi < 2; mi++)
#pragma unroll
      for (int ni = 0; ni < 4; ni++)
        acc[mi][ni] = __builtin_amdgcn_mfma_f32_16x16x32_bf16(af[mi], bf[ni], acc[mi][ni], 0, 0, 0);
    __syncthreads();
  }

#pragma unroll
  for (int mi = 0; mi < 2; mi++)
#pragma unroll
    for (int ni = 0; ni < 4; ni++)
#pragma unroll
      for (int r = 0; r < 4; r++) {
        int row = m0 + wr * 32 + mi * 16 + lq * 4 + r;
        int col = n0 + wc * 64 + ni * 16 + lr;
        out[(size_t)row * 1024 + col] = acc[mi][ni][r];
      }
}

// ---------------------------------------------------------------------------
// Attention, QBLK=64: 4 row-groups per wave, processed as 2 pairs per tile
// (QK -> softmax -> PV per pair; accs[2][4] reused). Grid 1024, 1-wave
// blocks; remap b=x>>8 -> every CU resident-holds one block per batch
// (perfect vlen balance at 4 blocks/CU). launch_bounds(64): no VGPR cap.
// Carries R22/R23: exp2, register clip-tails, plain-add interior bins.
// General window for 64 rows: (j0 > i0-79) && (j0 < i0+79).
// ---------------------------------------------------------------------------
__global__ __launch_bounds__(64) void attn_rpr_kernel(
    const unsigned short* __restrict__ Qb, const unsigned short* __restrict__ Kf,
    const unsigned short* __restrict__ Vf, const int* __restrict__ valid_lens,
    const unsigned short* __restrict__ Ekb, const unsigned short* __restrict__ Evtb,
    unsigned short* __restrict__ Ob) {
  __shared__ unsigned short sP[64 * 72];    // P / w-bins in A-layout (4 groups)
  __shared__ float sQE[64 * 34];            // qEk per row/bin
  __shared__ float sW[64 * 34];             // unnormalized bin sums

  const int lane = threadIdx.x;             // 0..63 (one wave)
  const int lr = lane & 15, lq = lane >> 4;
  // remap: b = round (x>>8). 256 blocks/round = 1/CU; all 1024 resident
  // (4/CU) -> each CU holds one block of every batch simultaneously.
  const int x = blockIdx.x;                 // 0..1023
  const int b = x >> 8;
  const int ss = x & 255;
  const int bh = b * 16 + (ss & 15);
  const int qx = ss >> 4;                   // 0..15
  const int vlen = valid_lens[b];
  const int i0 = qx * 64;
  const int colh = (bh & 15) * 64;
  const size_t bat = (size_t)b * 1024 * 1024;
  const int rbase = lq * 4;                 // first q-row within a group

  for (int i = lane; i < 64 * 34; i += 64) sW[i] = 0.f;

  // Q A-frags for 4 groups: rows i0 + g*16 + lr (row-major Qb)
  const unsigned short* gQ = Qb + bat + (size_t)(i0 + lr) * 1024 + colh + lq * 8;
  short8 aq0[4], aq1[4];
#pragma unroll
  for (int g = 0; g < 4; g++) {
    aq0[g] = *(const short8*)(gQ + (size_t)g * 16 * 1024);
    aq1[g] = *(const short8*)(gQ + (size_t)g * 16 * 1024 + 32);
  }

  // qEk via MFMA: D[i][t] = sum_d Q[i][d] * Ek[t][d], per group
#pragma unroll
  for (int ni = 0; ni < 3; ni++) {
    short8 be0 = *(const short8*)(Ekb + (ni * 16 + lr) * 64 + lq * 8);
    short8 be1 = *(const short8*)(Ekb + (ni * 16 + lr) * 64 + 32 + lq * 8);
    int t = ni * 16 + lr;
#pragma unroll
    for (int g = 0; g < 4; g++) {
      floatx4 aqe = (floatx4){0.f, 0.f, 0.f, 0.f};
      aqe = __builtin_amdgcn_mfma_f32_16x16x32_bf16(aq0[g], be0, aqe, 0, 0, 0);
      aqe = __builtin_amdgcn_mfma_f32_16x16x32_bf16(aq1[g], be1, aqe, 0, 0, 0);
      if (t < 33)
#pragma unroll
        for (int r = 0; r < 4; r++) sQE[(g * 16 + rbase + r) * 34 + t] = aqe[r];
    }
  }

  floatx4 acc_o[4][4];
#pragma unroll
  for (int g = 0; g < 4; g++)
#pragma unroll
    for (int nd = 0; nd < 4; nd++) acc_o[g][nd] = (floatx4){0.f, 0.f, 0.f, 0.f};
  float rs0[4][4], rs32[4][4];
#pragma unroll
  for (int g = 0; g < 4; g++)
#pragma unroll
    for (int r = 0; r < 4; r++) { rs0[g][r] = 0.f; rs32[g][r] = 0.f; }

  const int vcl = vlen < 1024 ? vlen : 1024;
  const int kt_max = (vcl + 63) >> 6;

  // fragment-layout bases: one contiguous 16KB region per (bh, kt)
  const unsigned short* gKf = Kf + (size_t)bh * 65536 + lane * 8;
  const unsigned short* gVf = Vf + (size_t)bh * 65536 + lane * 8;

  for (int kt = 0; kt < kt_max; kt++) {
    const int j0 = kt * 64;

    // K/V B-frags: 1KB coalesced per load (lane-contiguous fragment layout)
    short8 bk[4][2], bv[4][2];
#pragma unroll
    for (int ni = 0; ni < 4; ni++) {
      bk[ni][0] = *(const short8*)(gKf + (size_t)(kt * 8 + ni * 2 + 0) * 512);
      bk[ni][1] = *(const short8*)(gKf + (size_t)(kt * 8 + ni * 2 + 1) * 512);
    }
#pragma unroll
    for (int nd = 0; nd < 4; nd++) {
      bv[nd][0] = *(const short8*)(gVf + (size_t)(kt * 8 + nd * 2 + 0) * 512);
      bv[nd][1] = *(const short8*)(gVf + (size_t)(kt * 8 + nd * 2 + 1) * 512);
    }

    // t constant over the tile unless i0-79 < j0 < i0+79 (exact for 64 rows)
    const bool general = (j0 > i0 - 79) && (j0 < i0 + 79);
    const bool hi = (j0 >= i0 + 79);

    // process 4 groups as 2 pairs: QK -> softmax -> PV per pair (accs reused)
#pragma unroll
    for (int p = 0; p < 2; p++) {
      const int g0 = 2 * p;

      floatx4 accs[2][4];
      __builtin_amdgcn_s_setprio(1);
#pragma unroll
      for (int gg = 0; gg < 2; gg++)
#pragma unroll
        for (int ni = 0; ni < 4; ni++) {
          accs[gg][ni] = (floatx4){0.f, 0.f, 0.f, 0.f};
          accs[gg][ni] = __builtin_amdgcn_mfma_f32_16x16x32_bf16(aq0[g0 + gg], bk[ni][0], accs[gg][ni], 0, 0, 0);
          accs[gg][ni] = __builtin_amdgcn_mfma_f32_16x16x32_bf16(aq1[g0 + gg], bk[ni][1], accs[gg][ni], 0, 0, 0);
        }
      __builtin_amdgcn_s_setprio(0);

      if (!general) {
        const int tconst = hi ? 32 : 0;
#pragma unroll
        for (int gg = 0; gg < 2; gg++) {
          const int g = g0 + gg;
          float qe[4];
#pragma unroll
          for (int r = 0; r < 4; r++) qe[r] = sQE[(g * 16 + rbase + r) * 34 + tconst];
#pragma unroll
          for (int ni = 0; ni < 4; ni++)
#pragma unroll
            for (int r = 0; r < 4; r++) {
              int j_g = j0 + ni * 16 + lr;
              float pv = (j_g < vlen) ? exp2f(accs[gg][ni][r] + qe[r]) : 0.f;
              if (hi) rs32[g][r] += pv; else rs0[g][r] += pv;
              sP[(g * 16 + rbase + r) * 72 + ni * 16 + lr] = f2bf(pv);
            }
        }
      } else {
#pragma unroll
        for (int gg = 0; gg < 2; gg++) {
          const int g = g0 + gg;
#pragma unroll
          for (int ni = 0; ni < 4; ni++)
#pragma unroll
            for (int r = 0; r < 4; r++) {
              int i_g = i0 + g * 16 + rbase + r;
              int j_g = j0 + ni * 16 + lr;
              int ddr = j_g - i_g;
              int t = ddr < -16 ? 0 : (ddr > 16 ? 32 : ddr + 16);
              float pv = (j_g < vlen) ? exp2f(accs[gg][ni][r] + sQE[(g * 16 + rbase + r) * 34 + t]) : 0.f;
              // clip tails -> registers; interior bins: plain read-add-write
              // (race-free: distinct (row,t) per lane/step, wave-private sW)
              if (ddr <= -16)      rs0[g][r]  += pv;
              else if (ddr >= 16)  rs32[g][r] += pv;
              else {
                int idx = (g * 16 + rbase + r) * 34 + t;
                sW[idx] += pv;
              }
              sP[(g * 16 + rbase + r) * 72 + ni * 16 + lr] = f2bf(pv);
            }
        }
      }

      __builtin_amdgcn_s_setprio(1);
#pragma unroll
      for (int gg = 0; gg < 2; gg++) {
        const int g = g0 + gg;
        short8 ap0 = *(const short8*)(sP + (g * 16 + lr) * 72 + lq * 8);
        short8 ap1 = *(const short8*)(sP + (g * 16 + lr) * 72 + 32 + lq * 8);
#pragma unroll
        for (int nd = 0; nd < 4; nd++) {
          acc_o[g][nd] = __builtin_amdgcn_mfma_f32_16x16x32_bf16(ap0, bv[nd][0], acc_o[g][nd], 0, 0, 0);
          acc_o[g][nd] = __builtin_amdgcn_mfma_f32_16x16x32_bf16(ap1, bv[nd][1], acc_o[g][nd], 0, 0, 0);
        }
      }
      __builtin_amdgcn_s_setprio(0);
    }
  }

  // fold the register-accumulated bin-0/bin-32 sums into sW (one reduction)
#pragma unroll
  for (int x2 = 1; x2 < 16; x2 <<= 1)
#pragma unroll
    for (int g = 0; g < 4; g++)
#pragma unroll
      for (int r = 0; r < 4; r++) {
        rs0[g][r] += __shfl_xor(rs0[g][r], x2, 64);
        rs32[g][r] += __shfl_xor(rs32[g][r], x2, 64);
      }
  if (lr == 0)
#pragma unroll
    for (int g = 0; g < 4; g++)
#pragma unroll
      for (int r = 0; r < 4; r++) {
        sW[(g * 16 + rbase + r) * 34 + 0] += rs0[g][r];
        sW[(g * 16 + rbase + r) * 34 + 32] += rs32[g][r];
      }

  // w @ Ev via MFMA: pack sW rows into sP as bf16 [row][72] (k-pad to 64)
  {
    int row = lane >> 2;
    int c0 = (lane & 3) * 16;
    unsigned* sP32 = (unsigned*)sP;
#pragma unroll
    for (int g = 0; g < 4; g++)
#pragma unroll
      for (int q = 0; q < 8; q++) {
        int t0 = c0 + 2 * q, t1 = t0 + 1;
        float w0 = (t0 < 33) ? sW[(g * 16 + row) * 34 + t0] : 0.f;
        float w1 = (t1 < 33) ? sW[(g * 16 + row) * 34 + t1] : 0.f;
        sP32[(g * 16 + row) * 36 + (c0 >> 1) + q] = packbf(w0, w1);
      }
  }
#pragma unroll
  for (int g = 0; g < 4; g++) {
    short8 aw0 = *(const short8*)(sP + (g * 16 + lr) * 72 + lq * 8);
    short8 aw1 = *(const short8*)(sP + (g * 16 + lr) * 72 + 32 + lq * 8);
#pragma unroll
    for (int nd = 0; nd < 4; nd++) {
      short8 be0 = *(const short8*)(Evtb + (nd * 16 + lr) * 64 + lq * 8);
      short8 be1 = *(const short8*)(Evtb + (nd * 16 + lr) * 64 + 32 + lq * 8);
      acc_o[g][nd] = __builtin_amdgcn_mfma_f32_16x16x32_bf16(aw0, be0, acc_o[g][nd], 0, 0, 0);
      acc_o[g][nd] = __builtin_amdgcn_mfma_f32_16x16x32_bf16(aw1, be1, acc_o[g][nd], 0, 0, 0);
    }
  }

#pragma unroll
  for (int g = 0; g < 4; g++) {
    float linv[4];
#pragma unroll
    for (int r = 0; r < 4; r++) {
      float l = 0.f;
#pragma unroll
      for (int t = 0; t < 33; t++) l += sW[(g * 16 + rbase + r) * 34 + t];
      linv[r] = 1.f / l;
    }
#pragma unroll
    for (int nd = 0; nd < 4; nd++)
#pragma unroll
      for (int r = 0; r < 4; r++) {
        int row = i0 + g * 16 + rbase + r;
        Ob[bat + (size_t)row * 1024 + colh + nd * 16 + lr] =
            f2bf(acc_o[g][nd][r] * linv[r]);
      }
  }
}

// ---------------------------------------------------------------------------
extern "C" void kernel_launch(void* const* d_in, const int* in_sizes, int n_in,
                              void* d_out, int out_size, void* d_ws, size_t ws_size,
                              hipStream_t stream) {
  const float* queries = (const float*)d_in[0];
  const float* keys    = (const float*)d_in[1];
  const float* values  = (const float*)d_in[2];
  const int* valid_lens = (const int*)d_in[3];
  const float* Wq = (const float*)d_in[4];
  const float* Wk = (const float*)d_in[5];
  const float* Wv = (const float*)d_in[6];
  const float* Wo = (const float*)d_in[7];
  const float* Ek = (const float*)d_in[8];
  const float* Ev = (const float*)d_in[9];
  float* out = (float*)d_out;
  unsigned short* ws = (unsigned short*)d_ws;

  convert_all_kernel<<<dim3(2048, 1, 8), 256, 0, stream>>>(
      queries, keys, values, Wq, Wk, Wv, Wo, Ek, Ev, valid_lens, ws);
  proj_qkv_kernel<<<dim3(8, 32, 3), 256, 0, stream>>>(ws, valid_lens);
  attn_rpr_kernel<<<dim3(1024), 64, 0, stream>>>(
      ws + WS_QB, ws + WS_KB, ws + WS_VT, valid_lens, ws + WS_EKB, ws + WS_EVT, ws + WS_OB);
  out_proj_kernel<<<dim3(8, 64), 256, 0, stream>>>(ws + WS_OB, ws + WS_W + 3145728, out);
}

// Round 20
// 195.539 us; speedup vs baseline: 1.1561x; 1.1561x over previous
//
#include <hip/hip_runtime.h>

// ---------------------------------------------------------------------------
// MultiHeadAttentionWithRPR: B=4, S=1024, D=1024, H=16, hd=64, CLIP=16
// R25 = R23 verbatim (session best, 196.8us). R24's QBLK=64 regressed
// (226us): 180 VGPR -> 1 wave/SIMD, grid 1024 -> no co-resident waves to
// overlap the 2x-longer serial chain (occupancy 6%). QBLK=32 at ~100 VGPR
// with 2 waves/SIMD is the sweet spot; lever closed (16->32 ok, 32->64
// failed twice via spill and via occupancy).
// FINAL composite: convert fused; proj 128x128 (fragment-layout K/V out,
// Q scale 0.125*log2e); attn QBLK=32 1-wave blocks, fragment K/V 1KB
// coalesced loads, balanced batch-mix remap, exp2 softmax, register
// clip-tails, plain-add interior bins; out_proj 64x128 (2 blocks/CU).
// Session: 245.3 -> 196.8us (-19.8%).
// ---------------------------------------------------------------------------

typedef __attribute__((ext_vector_type(8))) short short8;   // 8 bf16
typedef __attribute__((ext_vector_type(4))) float floatx4;  // 4 f32 acc

__device__ __forceinline__ unsigned short f2bf(float f) {
  union { float f; unsigned u; } v; v.f = f;
  return (unsigned short)((v.u + 0x7fffu + ((v.u >> 16) & 1u)) >> 16); // RNE
}
__device__ __forceinline__ unsigned packbf(float lo, float hi) {
  return ((unsigned)f2bf(hi) << 16) | (unsigned)f2bf(lo);
}

__device__ __forceinline__ void gld16(const void* g, void* l) {
  __builtin_amdgcn_global_load_lds(
      (const __attribute__((address_space(1))) unsigned*)g,
      (__attribute__((address_space(3))) unsigned*)l, 16, 0, 0);
}

// ws layout (ushort element offsets)
#define WS_XQ  ((size_t)0)
#define WS_XK  ((size_t)4194304)
#define WS_XV  ((size_t)8388608)
#define WS_W   ((size_t)12582912)   // 4 x 1048576 (Wq,Wk,Wv,Wo)
#define WS_EKB ((size_t)16777216)   // 64x64 bf16 (rows t, zero-padded t>=33)
#define WS_EVT ((size_t)16781312)   // 64x64 bf16 (rows d, cols t, zero-padded)
#define WS_QB  ((size_t)16785408)
#define WS_KB  ((size_t)20979712)   // Kf fragment layout, 64 bh x 65536
#define WS_VT  ((size_t)25174016)   // Vf fragment layout, 64 bh x 65536
#define WS_OB  ((size_t)0)          // overlay on XQ (proj finished with it)

// ---------------------------------------------------------------------------
// One launch for all dtype conversions. z: 0..2 X(q,k,v), 3..6 W(q,k,v,o),
// 7 Ek/Ev pack. K/V rows >= vlen skipped (never used unmasked downstream).
// ---------------------------------------------------------------------------
__global__ __launch_bounds__(256) void convert_all_kernel(
    const float* __restrict__ q, const float* __restrict__ k,
    const float* __restrict__ v,
    const float* __restrict__ wq, const float* __restrict__ wk,
    const float* __restrict__ wv, const float* __restrict__ wo,
    const float* __restrict__ Ek, const float* __restrict__ Ev,
    const int* __restrict__ valid_lens, unsigned short* __restrict__ ws) {
  int z = blockIdx.z;
  if (z < 3) {
    const float* src = z == 0 ? q : (z == 1 ? k : v);
    unsigned short* dst = ws + (size_t)z * 4194304;
    size_t i = ((size_t)blockIdx.x * 256 + threadIdx.x) * 8;
    if (z > 0) {  // K/V: row s of batch b unused if s >= vlen
      int b = (int)(i >> 20), s = (int)((i >> 10) & 1023);
      if (s >= valid_lens[b]) return;
    }
    float4 a = *(const float4*)(src + i);
    float4 bb = *(const float4*)(src + i + 4);
    uint4 o = { packbf(a.x, a.y), packbf(a.z, a.w), packbf(bb.x, bb.y), packbf(bb.z, bb.w) };
    *(uint4*)(dst + i) = o;
  } else if (z < 7) {
    if (blockIdx.x >= 512) return;
    const float* src = (z == 3) ? wq : (z == 4 ? wk : (z == 5 ? wv : wo));
    unsigned short* dst = ws + WS_W + (size_t)(z - 3) * 1048576;
    size_t i = ((size_t)blockIdx.x * 256 + threadIdx.x) * 8;
    float4 a = *(const float4*)(src + i);
    float4 bb = *(const float4*)(src + i + 4);
    uint4 o = { packbf(a.x, a.y), packbf(a.z, a.w), packbf(bb.x, bb.y), packbf(bb.z, bb.w) };
    *(uint4*)(dst + i) = o;
  } else {
    if (blockIdx.x >= 4) return;
    int gid = blockIdx.x * 256 + threadIdx.x;   // 0..1023, x8 = Ekb+Evt
    unsigned short* ekb = ws + WS_EKB;
    int i0 = gid * 8;
    unsigned short vals[8];
#pragma unroll
    for (int u = 0; u < 8; u++) {
      int i = i0 + u;
      if (i < 4096) {                    // Ekb[t][d]
        int t = i >> 6, d = i & 63;
        vals[u] = (t < 33) ? f2bf(Ek[t * 64 + d]) : (unsigned short)0;
      } else {                           // Evt[d][t]
        int j = i - 4096;
        int d = j >> 6, t = j & 63;
        vals[u] = (t < 33) ? f2bf(Ev[t * 64 + d]) : (unsigned short)0;
      }
    }
    *(uint4*)(ekb + i0) = *(uint4*)vals;
  }
}

// ---------------------------------------------------------------------------
// NT GEMM 128x128 tile, BK=32, global_load_lds staging. A,W bf16 [.,1024].
// mode 0: bf16 row-major * scale (Q). mode 1: K fragment layout Kf.
// mode 2: V fragment layout Vf. mode 3: f32 row-major (final out).
// Fragment layouts (shorts): [bh*65536 + (kt*8 + frag*2 + half)*512
//   + lane*8 + dd], lane = lq*16 + lr of the CONSUMING attn wave:
//   Kf: s = kt*64 + frag*16 + lr, d = half*32 + lq*8 + dd
//   Vf: d = frag*16 + lr,         s = kt*64 + half*32 + lq*8 + dd
// ---------------------------------------------------------------------------
__device__ __forceinline__ void gemm128_body(
    const unsigned short* __restrict__ A, const unsigned short* __restrict__ W,
    unsigned short* __restrict__ Cb, float* __restrict__ Cf, int mode, float scale) {
  __shared__ unsigned short sA[128 * 32];
  __shared__ unsigned short sB[128 * 32];
  const int tid = threadIdx.x, wave = tid >> 6, lane = tid & 63;
  const int lr = lane & 15, lq = lane >> 4;
  const int wr = wave >> 1, wc = wave & 1;
  const int m0 = blockIdx.y * 128, n0 = blockIdx.x * 128;
  const int srow = lane >> 2, scol = (lane & 3) * 8;

  const unsigned short* gA0 = A + (size_t)(m0 + wave * 16 + srow) * 1024 + scol;
  const unsigned short* gA1 = gA0 + (size_t)64 * 1024;
  const unsigned short* gB0 = W + (size_t)(n0 + wave * 16 + srow) * 1024 + scol;
  const unsigned short* gB1 = gB0 + (size_t)64 * 1024;
  unsigned short* lA0 = sA + wave * 512;  unsigned short* lA1 = lA0 + 2048;
  unsigned short* lB0 = sB + wave * 512;  unsigned short* lB1 = lB0 + 2048;

  floatx4 acc[4][4];
#pragma unroll
  for (int mi = 0; mi < 4; mi++)
#pragma unroll
    for (int ni = 0; ni < 4; ni++) acc[mi][ni] = (floatx4){0.f, 0.f, 0.f, 0.f};

  for (int k0 = 0; k0 < 1024; k0 += 32) {
    gld16(gA0 + k0, lA0); gld16(gA1 + k0, lA1);
    gld16(gB0 + k0, lB0); gld16(gB1 + k0, lB1);
    __syncthreads();
    short8 af[4], bf[4];
#pragma unroll
    for (int mi = 0; mi < 4; mi++)
      af[mi] = *(const short8*)(sA + (wr * 64 + mi * 16 + lr) * 32 + lq * 8);
#pragma unroll
    for (int ni = 0; ni < 4; ni++)
      bf[ni] = *(const short8*)(sB + (wc * 64 + ni * 16 + lr) * 32 + lq * 8);
#pragma unroll
    for (int mi = 0; mi < 4; mi++)
#pragma unroll
      for (int ni = 0; ni < 4; ni++)
        acc[mi][ni] = __builtin_amdgcn_mfma_f32_16x16x32_bf16(af[mi], bf[ni], acc[mi][ni], 0, 0, 0);
    __syncthreads();
  }

  if (mode == 2) {       // V -> Vf fragment layout, one 8B store per quad
#pragma unroll
    for (int mi = 0; mi < 4; mi++)
#pragma unroll
      for (int ni = 0; ni < 4; ni++) {
        int col = n0 + wc * 64 + ni * 16 + lr;
        int h = col >> 6, d = col & 63;
        int rowg = m0 + wr * 64 + mi * 16 + lq * 4;
        int b = rowg >> 10, s = rowg & 1023;   // s..s+3, s % 4 == 0
        int bh = b * 16 + h;
        uint2 pk;
        pk.x = packbf(acc[mi][ni][0], acc[mi][ni][1]);
        pk.y = packbf(acc[mi][ni][2], acc[mi][ni][3]);
        size_t off = (size_t)bh * 65536
                   + (size_t)((s >> 6) * 8 + (d >> 4) * 2 + ((s >> 5) & 1)) * 512
                   + (size_t)((((s >> 3) & 3) * 16) + (d & 15)) * 8 + (s & 7);
        *(uint2*)(Cb + off) = pk;
      }
  } else if (mode == 1) { // K -> Kf fragment layout, scalar stores
#pragma unroll
    for (int mi = 0; mi < 4; mi++)
#pragma unroll
      for (int ni = 0; ni < 4; ni++)
#pragma unroll
        for (int r = 0; r < 4; r++) {
          int rowg = m0 + wr * 64 + mi * 16 + lq * 4 + r;
          int col = n0 + wc * 64 + ni * 16 + lr;
          int b = rowg >> 10, s = rowg & 1023;
          int h = col >> 6, d = col & 63;
          int bh = b * 16 + h;
          size_t off = (size_t)bh * 65536
                     + (size_t)((s >> 6) * 8 + ((s & 63) >> 4) * 2 + (d >> 5)) * 512
                     + (size_t)((((d & 31) >> 3) * 16) + (s & 15)) * 8 + (d & 7);
          Cb[off] = f2bf(acc[mi][ni][r]);
        }
  } else if (mode == 3) {
#pragma unroll
    for (int mi = 0; mi < 4; mi++)
#pragma unroll
      for (int ni = 0; ni < 4; ni++)
#pragma unroll
        for (int r = 0; r < 4; r++) {
          int row = m0 + wr * 64 + mi * 16 + lq * 4 + r;
          int col = n0 + wc * 64 + ni * 16 + lr;
          Cf[(size_t)row * 1024 + col] = acc[mi][ni][r];
        }
  } else {               // mode 0: Q, row-major bf16 * scale
#pragma unroll
    for (int mi = 0; mi < 4; mi++)
#pragma unroll
      for (int ni = 0; ni < 4; ni++)
#pragma unroll
        for (int r = 0; r < 4; r++) {
          int row = m0 + wr * 64 + mi * 16 + lq * 4 + r;
          int col = n0 + wc * 64 + ni * 16 + lr;
          Cb[(size_t)row * 1024 + col] = f2bf(acc[mi][ni][r] * scale);
        }
  }
}

__global__ __launch_bounds__(256, 3) void proj_qkv_kernel(
    unsigned short* __restrict__ ws, const int* __restrict__ valid_lens) {
  int z = blockIdx.z;
  if (z > 0) {  // K/V: whole tile unused if its first row >= vlen
    int m0 = blockIdx.y * 128;
    if ((m0 & 1023) >= valid_lens[m0 >> 10]) return;
  }
  const unsigned short* A = ws + (size_t)z * 4194304;
  const unsigned short* W = ws + WS_W + (size_t)z * 1048576;
  unsigned short* Cb = (z == 0) ? ws + WS_QB : (z == 1 ? ws + WS_KB : ws + WS_VT);
  int mode = (z == 2) ? 2 : (z == 0 ? 0 : 1);
  // fold 1/sqrt(hd) AND log2(e) into Q ONLY: s2 = log2e*(q.k + q.Ek)/8,
  // softmax uses exp2(s2) == exp(s) exactly. K stays unscaled.
  float scale = (z == 0) ? (0.125f * 1.4426950408889634f) : 1.0f;
  gemm128_body(A, W, Cb, nullptr, mode, scale);
}

// ---------------------------------------------------------------------------
// out_proj: 64x128 tile (512 blocks = 2/CU; 128^2 gave 256 = 1/CU and fully
// exposed the per-K-step barrier drain). 4 waves as 2x2 over (64,128);
// each wave 32x64 = acc[2][4]. f32 row-major epilogue.
// ---------------------------------------------------------------------------
__global__ __launch_bounds__(256, 4) void out_proj_kernel(
    const unsigned short* __restrict__ Ob, const unsigned short* __restrict__ Wo,
    float* __restrict__ out) {
  __shared__ unsigned short sA[64 * 32];
  __shared__ unsigned short sB[128 * 32];
  const int tid = threadIdx.x, wave = tid >> 6, lane = tid & 63;
  const int lr = lane & 15, lq = lane >> 4;
  const int wr = wave >> 1, wc = wave & 1;
  const int m0 = blockIdx.y * 64, n0 = blockIdx.x * 128;
  const int srow = lane >> 2, scol = (lane & 3) * 8;

  const unsigned short* gA0 = Ob + (size_t)(m0 + wave * 16 + srow) * 1024 + scol;
  const unsigned short* gB0 = Wo + (size_t)(n0 + wave * 16 + srow) * 1024 + scol;
  const unsigned short* gB1 = gB0 + (size_t)64 * 1024;
  unsigned short* lA0 = sA + wave * 512;
  unsigned short* lB0 = sB + wave * 512;  unsigned short* lB1 = lB0 + 2048;

  floatx4 acc[2][4];
#pragma unroll
  for (int mi = 0; mi < 2; mi++)
#pragma unroll
    for (int ni = 0; ni < 4; ni++) acc[mi][ni] = (floatx4){0.f, 0.f, 0.f, 0.f};

  for (int k0 = 0; k0 < 1024; k0 += 32) {
    gld16(gA0 + k0, lA0);
    gld16(gB0 + k0, lB0); gld16(gB1 + k0, lB1);
    __syncthreads();
    short8 af[2], bf[4];
#pragma unroll
    for (int mi = 0; mi < 2; mi++)
      af[mi] = *(const short8*)(sA + (wr * 32 + mi * 16 + lr) * 32 + lq * 8);
#pragma unroll
    for (int ni = 0; ni < 4; ni++)
      bf[ni] = *(const short8*)(sB + (wc * 64 + ni * 16 + lr) * 32 + lq * 8);
#pragma unroll
    for (int mi = 0; mi < 2; mi++)
#pragma unroll
      for (int ni = 0; ni < 4; ni++)
        acc[mi][ni] = __builtin_amdgcn_mfma_f32_16x16x32_bf16(af[mi], bf[ni], acc[mi][ni], 0, 0, 0);
    __syncthreads();
  }

#pragma unroll
  for (int mi = 0; mi < 2; mi++)
#pragma unroll
    for (int ni = 0; ni < 4; ni++)
#pragma unroll
      for (int r = 0; r < 4; r++) {
        int row = m0 + wr * 32 + mi * 16 + lq * 4 + r;
        int col = n0 + wc * 64 + ni * 16 + lr;
        out[(size_t)row * 1024 + col] = acc[mi][ni][r];
      }
}

// ---------------------------------------------------------------------------
// Attention (final: QBLK=32, fragment K/V, balanced remap, exp2, register
// clip-tails, plain-add interior bins). General path: interior bins
// (t=1..31) plain read-add-write (race-free: distinct (row,t) per lane per
// step, sW wave-private); clip tails in rs0/rs32 registers.
// Unnormalized softmax: p = exp2(s2); l = sum of 33 clip-bins.
// General-tile window for 32 rows: (j0 > i0-79) && (j0 < i0+47).
// ---------------------------------------------------------------------------
__global__ __launch_bounds__(64, 2) void attn_rpr_kernel(
    const unsigned short* __restrict__ Qb, const unsigned short* __restrict__ Kf,
    const unsigned short* __restrict__ Vf, const int* __restrict__ valid_lens,
    const unsigned short* __restrict__ Ekb, const unsigned short* __restrict__ Evtb,
    unsigned short* __restrict__ Ob) {
  __shared__ unsigned short sP[32 * 72];    // P / w-bins in A-layout (2 groups)
  __shared__ float sQE[32 * 34];            // qEk per row/bin
  __shared__ float sW[32 * 34];             // unnormalized bin sums

  const int lane = threadIdx.x;             // 0..63 (one wave)
  const int lr = lane & 15, lq = lane >> 4;
  // balanced remap: batches cycle across dispatch rounds, heads across slots
  const int x = blockIdx.x;                 // 0..2047
  const int rr = x >> 8, ss = x & 255;
  const int b = rr & 3;
  const int bh = b * 16 + (ss & 15);
  const int qx = ((rr >> 2) << 4) + (ss >> 4);
  const int vlen = valid_lens[b];
  const int i0 = qx * 32;
  const int colh = (bh & 15) * 64;
  const size_t bat = (size_t)b * 1024 * 1024;
  const int rbase = lq * 4;                 // first q-row within a group

  for (int i = lane; i < 32 * 34; i += 64) sW[i] = 0.f;

  // Q A-frags for both groups: rows i0 + g*16 + lr (row-major Qb)
  const unsigned short* gQ = Qb + bat + (size_t)(i0 + lr) * 1024 + colh + lq * 8;
  short8 aq0[2], aq1[2];
#pragma unroll
  for (int g = 0; g < 2; g++) {
    aq0[g] = *(const short8*)(gQ + (size_t)g * 16 * 1024);
    aq1[g] = *(const short8*)(gQ + (size_t)g * 16 * 1024 + 32);
  }

  // qEk via MFMA: D[i][t] = sum_d Q[i][d] * Ek[t][d], per group
#pragma unroll
  for (int ni = 0; ni < 3; ni++) {
    short8 be0 = *(const short8*)(Ekb + (ni * 16 + lr) * 64 + lq * 8);
    short8 be1 = *(const short8*)(Ekb + (ni * 16 + lr) * 64 + 32 + lq * 8);
    int t = ni * 16 + lr;
#pragma unroll
    for (int g = 0; g < 2; g++) {
      floatx4 aqe = (floatx4){0.f, 0.f, 0.f, 0.f};
      aqe = __builtin_amdgcn_mfma_f32_16x16x32_bf16(aq0[g], be0, aqe, 0, 0, 0);
      aqe = __builtin_amdgcn_mfma_f32_16x16x32_bf16(aq1[g], be1, aqe, 0, 0, 0);
      if (t < 33)
#pragma unroll
        for (int r = 0; r < 4; r++) sQE[(g * 16 + rbase + r) * 34 + t] = aqe[r];
    }
  }

  floatx4 acc_o[2][4];
#pragma unroll
  for (int g = 0; g < 2; g++)
#pragma unroll
    for (int nd = 0; nd < 4; nd++) acc_o[g][nd] = (floatx4){0.f, 0.f, 0.f, 0.f};
  float rs0[2][4] = {{0.f,0.f,0.f,0.f},{0.f,0.f,0.f,0.f}};
  float rs32[2][4] = {{0.f,0.f,0.f,0.f},{0.f,0.f,0.f,0.f}};

  const int vcl = vlen < 1024 ? vlen : 1024;
  const int kt_max = (vcl + 63) >> 6;

  // fragment-layout bases: one contiguous 16KB region per (bh, kt)
  const unsigned short* gKf = Kf + (size_t)bh * 65536 + lane * 8;
  const unsigned short* gVf = Vf + (size_t)bh * 65536 + lane * 8;

  for (int kt = 0; kt < kt_max; kt++) {
    const int j0 = kt * 64;

    // K/V B-frags: 1KB coalesced per load (lane-contiguous fragment layout)
    short8 bk[4][2], bv[4][2];
#pragma unroll
    for (int ni = 0; ni < 4; ni++) {
      bk[ni][0] = *(const short8*)(gKf + (size_t)(kt * 8 + ni * 2 + 0) * 512);
      bk[ni][1] = *(const short8*)(gKf + (size_t)(kt * 8 + ni * 2 + 1) * 512);
    }
#pragma unroll
    for (int nd = 0; nd < 4; nd++) {
      bv[nd][0] = *(const short8*)(gVf + (size_t)(kt * 8 + nd * 2 + 0) * 512);
      bv[nd][1] = *(const short8*)(gVf + (size_t)(kt * 8 + nd * 2 + 1) * 512);
    }

    floatx4 accs[2][4];
    __builtin_amdgcn_s_setprio(1);
#pragma unroll
    for (int g = 0; g < 2; g++)
#pragma unroll
      for (int ni = 0; ni < 4; ni++) {
        accs[g][ni] = (floatx4){0.f, 0.f, 0.f, 0.f};
        accs[g][ni] = __builtin_amdgcn_mfma_f32_16x16x32_bf16(aq0[g], bk[ni][0], accs[g][ni], 0, 0, 0);
        accs[g][ni] = __builtin_amdgcn_mfma_f32_16x16x32_bf16(aq1[g], bk[ni][1], accs[g][ni], 0, 0, 0);
      }
    __builtin_amdgcn_s_setprio(0);

    // t constant over the tile unless i0-79 < j0 < i0+47 (exact for 32 rows)
    const bool general = (j0 > i0 - 79) && (j0 < i0 + 47);
    if (!general) {
      const bool hi = (j0 >= i0 + 47);
      const int tconst = hi ? 32 : 0;
#pragma unroll
      for (int g = 0; g < 2; g++) {
        float qe[4];
#pragma unroll
        for (int r = 0; r < 4; r++) qe[r] = sQE[(g * 16 + rbase + r) * 34 + tconst];
#pragma unroll
        for (int ni = 0; ni < 4; ni++)
#pragma unroll
          for (int r = 0; r < 4; r++) {
            int j_g = j0 + ni * 16 + lr;
            float pv = (j_g < vlen) ? exp2f(accs[g][ni][r] + qe[r]) : 0.f;
            if (hi) rs32[g][r] += pv; else rs0[g][r] += pv;
            sP[(g * 16 + rbase + r) * 72 + ni * 16 + lr] = f2bf(pv);
          }
      }
    } else {
#pragma unroll
      for (int g = 0; g < 2; g++)
#pragma unroll
        for (int ni = 0; ni < 4; ni++)
#pragma unroll
          for (int r = 0; r < 4; r++) {
            int i_g = i0 + g * 16 + rbase + r;
            int j_g = j0 + ni * 16 + lr;
            int ddr = j_g - i_g;
            int t = ddr < -16 ? 0 : (ddr > 16 ? 32 : ddr + 16);
            float pv = (j_g < vlen) ? exp2f(accs[g][ni][r] + sQE[(g * 16 + rbase + r) * 34 + t]) : 0.f;
            // clip tails -> registers; interior bins: plain read-add-write
            // (race-free: distinct (row,t) per lane per step, wave-private sW)
            if (ddr <= -16)      rs0[g][r]  += pv;
            else if (ddr >= 16)  rs32[g][r] += pv;
            else {
              int idx = (g * 16 + rbase + r) * 34 + t;
              sW[idx] += pv;
            }
            sP[(g * 16 + rbase + r) * 72 + ni * 16 + lr] = f2bf(pv);
          }
    }

    __builtin_amdgcn_s_setprio(1);
#pragma unroll
    for (int g = 0; g < 2; g++) {
      short8 ap0 = *(const short8*)(sP + (g * 16 + lr) * 72 + lq * 8);
      short8 ap1 = *(const short8*)(sP + (g * 16 + lr) * 72 + 32 + lq * 8);
#pragma unroll
      for (int nd = 0; nd < 4; nd++) {
        acc_o[g][nd] = __builtin_amdgcn_mfma_f32_16x16x32_bf16(ap0, bv[nd][0], acc_o[g][nd], 0, 0, 0);
        acc_o[g][nd] = __builtin_amdgcn_mfma_f32_16x16x32_bf16(ap1, bv[nd][1], acc_o[g][nd], 0, 0, 0);
      }
    }
    __builtin_amdgcn_s_setprio(0);
  }

  // fold the register-accumulated bin-0/bin-32 sums into sW (one reduction)
#pragma unroll
  for (int x2 = 1; x2 < 16; x2 <<= 1)
#pragma unroll
    for (int g = 0; g < 2; g++)
#pragma unroll
      for (int r = 0; r < 4; r++) {
        rs0[g][r] += __shfl_xor(rs0[g][r], x2, 64);
        rs32[g][r] += __shfl_xor(rs32[g][r], x2, 64);
      }
  if (lr == 0)
#pragma unroll
    for (int g = 0; g < 2; g++)
#pragma unroll
      for (int r = 0; r < 4; r++) {
        sW[(g * 16 + rbase + r) * 34 + 0] += rs0[g][r];
        sW[(g * 16 + rbase + r) * 34 + 32] += rs32[g][r];
      }

  // w @ Ev via MFMA: pack sW rows into sP as bf16 [row][72] (k-pad to 64)
  {
    int row = lane >> 2;
    int c0 = (lane & 3) * 16;
    unsigned* sP32 = (unsigned*)sP;
#pragma unroll
    for (int g = 0; g < 2; g++)
#pragma unroll
      for (int q = 0; q < 8; q++) {
        int t0 = c0 + 2 * q, t1 = t0 + 1;
        float w0 = (t0 < 33) ? sW[(g * 16 + row) * 34 + t0] : 0.f;
        float w1 = (t1 < 33) ? sW[(g * 16 + row) * 34 + t1] : 0.f;
        sP32[(g * 16 + row) * 36 + (c0 >> 1) + q] = packbf(w0, w1);
      }
  }
#pragma unroll
  for (int g = 0; g < 2; g++) {
    short8 aw0 = *(const short8*)(sP + (g * 16 + lr) * 72 + lq * 8);
    short8 aw1 = *(const short8*)(sP + (g * 16 + lr) * 72 + 32 + lq * 8);
#pragma unroll
    for (int nd = 0; nd < 4; nd++) {
      short8 be0 = *(const short8*)(Evtb + (nd * 16 + lr) * 64 + lq * 8);
      short8 be1 = *(const short8*)(Evtb + (nd * 16 + lr) * 64 + 32 + lq * 8);
      acc_o[g][nd] = __builtin_amdgcn_mfma_f32_16x16x32_bf16(aw0, be0, acc_o[g][nd], 0, 0, 0);
      acc_o[g][nd] = __builtin_amdgcn_mfma_f32_16x16x32_bf16(aw1, be1, acc_o[g][nd], 0, 0, 0);
    }
  }

#pragma unroll
  for (int g = 0; g < 2; g++) {
    float linv[4];
#pragma unroll
    for (int r = 0; r < 4; r++) {
      float l = 0.f;
#pragma unroll
      for (int t = 0; t < 33; t++) l += sW[(g * 16 + rbase + r) * 34 + t];
      linv[r] = 1.f / l;
    }
#pragma unroll
    for (int nd = 0; nd < 4; nd++)
#pragma unroll
      for (int r = 0; r < 4; r++) {
        int row = i0 + g * 16 + rbase + r;
        Ob[bat + (size_t)row * 1024 + colh + nd * 16 + lr] =
            f2bf(acc_o[g][nd][r] * linv[r]);
      }
  }
}

// ---------------------------------------------------------------------------
extern "C" void kernel_launch(void* const* d_in, const int* in_sizes, int n_in,
                              void* d_out, int out_size, void* d_ws, size_t ws_size,
                              hipStream_t stream) {
  const float* queries = (const float*)d_in[0];
  const float* keys    = (const float*)d_in[1];
  const float* values  = (const float*)d_in[2];
  const int* valid_lens = (const int*)d_in[3];
  const float* Wq = (const float*)d_in[4];
  const float* Wk = (const float*)d_in[5];
  const float* Wv = (const float*)d_in[6];
  const float* Wo = (const float*)d_in[7];
  const float* Ek = (const float*)d_in[8];
  const float* Ev = (const float*)d_in[9];
  float* out = (float*)d_out;
  unsigned short* ws = (unsigned short*)d_ws;

  convert_all_kernel<<<dim3(2048, 1, 8), 256, 0, stream>>>(
      queries, keys, values, Wq, Wk, Wv, Wo, Ek, Ev, valid_lens, ws);
  proj_qkv_kernel<<<dim3(8, 32, 3), 256, 0, stream>>>(ws, valid_lens);
  attn_rpr_kernel<<<dim3(2048), 64, 0, stream>>>(
      ws + WS_QB, ws + WS_KB, ws + WS_VT, valid_lens, ws + WS_EKB, ws + WS_EVT, ws + WS_OB);
  out_proj_kernel<<<dim3(8, 64), 256, 0, stream>>>(ws + WS_OB, ws + WS_W + 3145728, out);
}